// Round 8
// baseline (3286.856 us; speedup 1.0000x reference)
//
#include <hip/hip_runtime.h>
#include <cstdint>
#include <cstddef>

// ---------------------------------------------------------------------------
// GAT x3 (exact JAX-threefry dropout, PARTITIONABLE mode) + SAGPool x7.
// Round 12 (all changes bitwise-preserving):
//  * epi_k fused into gat_out_k epilogue: identical per-element formula on
//    the just-computed acc (threefry index t = node*200+col unchanged) ->
//    -3 launches, -240MB RMW traffic.
//  * edge_max_k + menc memset fused into eeden_k: per-node serial integer
//    max over the same order-encoded values the atomicMax produced (max is
//    commutative/idempotent -> bit-identical m).
//  * rsmall_k: single-block 4-pass stable LSD radix for n <= 4096 (last 3
//    pool iterations): 9-launch chain -> 1 launch, same stable-sort result.
//  * Round-6 structure kept: pk pack (one 8B load/edge in gat_out),
//    pool_agg+score fusion, depth-4 rolling pipelines, gemm float4 epilogue.
// All segment ops remain deterministic + np-association-matched (CSR serial).
// ---------------------------------------------------------------------------

__host__ __device__ inline void tf_round(uint32_t &x0, uint32_t &x1, int r) {
  x0 += x1;
  x1 = (x1 << r) | (x1 >> (32 - r));
  x1 ^= x0;
}

// Exact jax threefry2x32 (Random123 KAT: key(0,0),ctr(0,0) -> 6b200159 99ba4efe)
__host__ __device__ inline void threefry2x32(uint32_t k0, uint32_t k1,
                                             uint32_t &x0, uint32_t &x1) {
  uint32_t ks2 = k0 ^ k1 ^ 0x1BD11BDAu;
  x0 += k0; x1 += k1;
  tf_round(x0, x1, 13); tf_round(x0, x1, 15); tf_round(x0, x1, 26); tf_round(x0, x1, 6);
  x0 += k1; x1 += ks2 + 1u;
  tf_round(x0, x1, 17); tf_round(x0, x1, 29); tf_round(x0, x1, 16); tf_round(x0, x1, 24);
  x0 += ks2; x1 += k0 + 2u;
  tf_round(x0, x1, 13); tf_round(x0, x1, 15); tf_round(x0, x1, 26); tf_round(x0, x1, 6);
  x0 += k0; x1 += k1 + 3u;
  tf_round(x0, x1, 17); tf_round(x0, x1, 29); tf_round(x0, x1, 16); tf_round(x0, x1, 24);
  x0 += k1; x1 += ks2 + 4u;
  tf_round(x0, x1, 13); tf_round(x0, x1, 15); tf_round(x0, x1, 26); tf_round(x0, x1, 6);
  x0 += ks2; x1 += k0 + 5u;
}

// ---------------- GEMM: C[M x 200] = A[M x K] @ B[K x 200], fp32 -------------
__global__ __launch_bounds__(256) void gemm200_k(
    const float* __restrict__ A, const float* __restrict__ B,
    float* __restrict__ C, int M, int K) {
  __shared__ float As[128 * 9];                 // pad 8->9: conflict-free reads
  __shared__ __align__(16) float Bs[8][208];
  int tid = threadIdx.x;
  int m0 = blockIdx.x * 128;
  int r = tid >> 2;
  int colBase = (tid & 3) * 52;
  int nq = (colBase == 156) ? 11 : 13;          // valid float4s in epilogue
  float acc0[52], acc1[52];
#pragma unroll
  for (int q = 0; q < 52; q++) { acc0[q] = 0.f; acc1[q] = 0.f; }

  // staging assignments
  int arow = tid >> 1;
  int ac = (tid & 1) * 4;
  int gmA = m0 + arow;
  const float* Aptr = A + (size_t)gmA * K + ac;
  int bk0 = tid / 50, bc0 = (tid - bk0 * 50) * 4;
  int t2 = tid + 256;
  int bk1 = t2 / 50, bc1 = (t2 - bk1 * 50) * 4;
  bool hasB1 = (t2 < 400);

  // prefetch tile 0 into registers
  float4 va = make_float4(0.f, 0.f, 0.f, 0.f);
  if (gmA < M) va = *(const float4*)(Aptr);
  float4 vb0 = *(const float4*)(B + (size_t)bk0 * 200 + bc0);
  float4 vb1 = make_float4(0.f, 0.f, 0.f, 0.f);
  if (hasB1) vb1 = *(const float4*)(B + (size_t)bk1 * 200 + bc1);

  for (int k0 = 0; k0 < K; k0 += 8) {
    // commit staged registers to LDS
    As[arow * 9 + ac + 0] = va.x;
    As[arow * 9 + ac + 1] = va.y;
    As[arow * 9 + ac + 2] = va.z;
    As[arow * 9 + ac + 3] = va.w;
    *(float4*)(&Bs[bk0][bc0]) = vb0;
    if (hasB1) *(float4*)(&Bs[bk1][bc1]) = vb1;
    __syncthreads();
    // issue next-tile global loads; they land under the FMA phase below
    int kn = k0 + 8;
    if (kn < K) {
      if (gmA < M) va = *(const float4*)(Aptr + kn);
      vb0 = *(const float4*)(B + (size_t)(kn + bk0) * 200 + bc0);
      if (hasB1) vb1 = *(const float4*)(B + (size_t)(kn + bk1) * 200 + bc1);
    }
#pragma unroll
    for (int kk = 0; kk < 8; kk++) {
      float a0 = As[r * 9 + kk];
      float a1 = As[(r + 64) * 9 + kk];
#pragma unroll
      for (int q = 0; q < 13; q++) {
        float4 b = *(const float4*)(&Bs[kk][colBase + 4 * q]);
        acc0[4 * q + 0] += a0 * b.x; acc0[4 * q + 1] += a0 * b.y;
        acc0[4 * q + 2] += a0 * b.z; acc0[4 * q + 3] += a0 * b.w;
        acc1[4 * q + 0] += a1 * b.x; acc1[4 * q + 1] += a1 * b.y;
        acc1[4 * q + 2] += a1 * b.z; acc1[4 * q + 3] += a1 * b.w;
      }
    }
    __syncthreads();
  }
  // epilogue: coalesced float4 stores
  int gm0 = m0 + r, gm1 = m0 + r + 64;
#pragma unroll
  for (int q = 0; q < 13; q++) {
    if (q < nq) {
      int col = colBase + 4 * q;
      float4 v0 = make_float4(acc0[4 * q + 0], acc0[4 * q + 1],
                              acc0[4 * q + 2], acc0[4 * q + 3]);
      float4 v1 = make_float4(acc1[4 * q + 0], acc1[4 * q + 1],
                              acc1[4 * q + 2], acc1[4 * q + 3]);
      if (gm0 < M) *(float4*)(C + (size_t)gm0 * 200 + col) = v0;
      if (gm1 < M) *(float4*)(C + (size_t)gm1 * 200 + col) = v1;
    }
  }
}

// ---------------- dual dot: o1[i]=H[i]·v1, o2[i]=H[i]·v2 (one wave/node) -----
__global__ __launch_bounds__(256) void dual_dot_k(
    const float* __restrict__ H, const float* __restrict__ v1,
    const float* __restrict__ v2, float* __restrict__ o1,
    float* __restrict__ o2, int n) {
  int wave = blockIdx.x * 4 + (threadIdx.x >> 6);
  int lane = threadIdx.x & 63;
  if (wave >= n) return;
  const float* row = H + (size_t)wave * 200;
  float s1 = 0.f, s2 = 0.f;
  for (int d = lane; d < 200; d += 64) {
    float h = row[d];
    s1 += h * v1[d];
    s2 += h * v2[d];
  }
  for (int off = 32; off; off >>= 1) {
    s1 += __shfl_down(s1, off);
    s2 += __shfl_down(s2, off);
  }
  if (lane == 0) { o1[wave] = s1; o2[wave] = s2; }
}

// ---------------- CSR build (dst-sorted, stable by edge index) ---------------
__global__ __launch_bounds__(256) void indeg_k(const int* __restrict__ dst,
                                               int* __restrict__ cnt, int E) {
  int e = blockIdx.x * 256 + threadIdx.x;
  if (e < E) atomicAdd(&cnt[dst[e]], 1);
}

// single block, 256 threads: exclusive scan cnt[0..N) -> rowptr[0..N]
__global__ __launch_bounds__(256) void scan_k(const int* __restrict__ cnt,
                                              int* __restrict__ rowptr, int N) {
  __shared__ int psum[256];
  int t = threadIdx.x;
  int CH = (N + 255) / 256;
  int beg = t * CH, end = min(beg + CH, N);
  if (beg > N) { beg = N; }
  int s = 0;
  for (int i = beg; i < end; i++) s += cnt[i];
  psum[t] = s;
  __syncthreads();
  if (t == 0) {
    int run = 0;
    for (int i = 0; i < 256; i++) { int v = psum[i]; psum[i] = run; run += v; }
  }
  __syncthreads();
  int run = psum[t];
  for (int i = beg; i < end; i++) { rowptr[i] = run; run += cnt[i]; }
  if (end == N && beg <= N) rowptr[N] = run;
}

__global__ __launch_bounds__(256) void cpyint_k(const int* __restrict__ a,
                                                int* __restrict__ b, int n) {
  int i = blockIdx.x * 256 + threadIdx.x;
  if (i < n) b[i] = a[i];
}

__global__ __launch_bounds__(256) void place_k(const int* __restrict__ dst,
                                               int* __restrict__ curs,
                                               int* __restrict__ csr, int E) {
  int e = blockIdx.x * 256 + threadIdx.x;
  if (e >= E) return;
  int pos = atomicAdd(&curs[dst[e]], 1);
  csr[pos] = e;
}

__global__ __launch_bounds__(256) void sortrow_k(const int* __restrict__ rowptr,
                                                 int* __restrict__ csr, int N) {
  int d = blockIdx.x * 256 + threadIdx.x;
  if (d >= N) return;
  int b = rowptr[d], e2 = rowptr[d + 1];
  for (int i = b + 1; i < e2; i++) {
    int v = csr[i];
    int j = i - 1;
    while (j >= b && csr[j] > v) { csr[j + 1] = csr[j]; j--; }
    csr[j + 1] = v;
  }
}

// ---------------- GAT edge softmax (deterministic, np order) -----------------
__device__ inline float dec_ord(unsigned enc) {
  unsigned b = (enc & 0x80000000u) ? (enc ^ 0x80000000u) : ~enc;
  return __uint_as_float(b);
}

__device__ inline unsigned enc_ord(float ev) {
  unsigned b = __float_as_uint(ev);
  return (b & 0x80000000u) ? ~b : (b | 0x80000000u);
}

// Fused max + ee + den + CSR-position pack: one thread per node d, serial
// over its CSR row. Pass 1: integer max of order-encoded leaky values over
// {row edges} U {self} -- identical result to the old memset(0)+atomicMax
// (max is commutative/idempotent on the encoding; enc > 0 always so the 0
// init never wins). Pass 2: ee/pk/den in EXACT old ee_k/den_k order (serial
// __fadd_rn, self-loop last) -> bitwise identical.
__global__ __launch_bounds__(256) void eeden_k(
    const int* __restrict__ rowptr, const int* __restrict__ csr,
    const int* __restrict__ src, const float* __restrict__ as_,
    const float* __restrict__ ad_, int2* __restrict__ pk,
    float* __restrict__ eeS, float* __restrict__ den, int N) {
  int d = blockIdx.x * 256 + threadIdx.x;
  if (d >= N) return;
  float adv = ad_[d];
  int b = rowptr[d], e2 = rowptr[d + 1];
  unsigned mx = 0u;
  for (int i = b; i < e2; i++) {
    int sv = src[csr[i]];
    float v = as_[sv] + adv;
    float ev = (v >= 0.f) ? v : 0.2f * v;
    mx = max(mx, enc_ord(ev));
  }
  {
    float v = as_[d] + adv;  // self-loop term
    float ev = (v >= 0.f) ? v : 0.2f * v;
    mx = max(mx, enc_ord(ev));
  }
  float m = dec_ord(mx);
  float s = 0.f;
  for (int i = b; i < e2; i++) {
    int sv = src[csr[i]];
    float v = as_[sv] + adv;
    float ev = (v >= 0.f) ? v : 0.2f * v;
    float ee = expf(ev - m);
    pk[i] = make_int2(sv, __float_as_int(ee));
    s = __fadd_rn(s, ee);
  }
  float vS = as_[d] + adv;
  float evS = (vS >= 0.f) ? vS : 0.2f * vS;
  float eS = expf(evS - m);
  eeS[d] = eS;
  s = __fadd_rn(s, eS);
  den[d] = s;
}

#define GLD(s) (*(const float4*)(Hl + (size_t)(s) * 200))
#define ACC(W_, H_)                                    \
  acc.x = __fadd_rn(acc.x, __fmul_rn((W_), (H_).x));   \
  acc.y = __fadd_rn(acc.y, __fmul_rn((W_), (H_).y));   \
  acc.z = __fadd_rn(acc.z, __fmul_rn((W_), (H_).z));   \
  acc.w = __fadd_rn(acc.w, __fmul_rn((W_), (H_).w));

// GAT out + fused epilogue (bias/relu/threefry-dropout, bitwise = old epi_k
// on the identical just-computed value; threefry counter t = node*200+col).
// Wave per node, serial over edges (edge-index order, self last). Depth-4
// rolling pipeline; per edge ONE contiguous 8B pk load. w = __fdiv_rn(ee,den)
// is bitwise alpha_k's division. Pad slots read the node's own cache-hot row
// with w=0 -> exact FP no-ops.
__global__ __launch_bounds__(256) void gat_out_k(
    const int* __restrict__ rowptr, const int2* __restrict__ pk,
    const float* __restrict__ eeS, const float* __restrict__ den,
    const float* __restrict__ HW, const float* __restrict__ bias,
    float* __restrict__ OUT, uint32_t tk0, uint32_t tk1, int N) {
  int node = blockIdx.x * 4 + (threadIdx.x >> 6);
  int lane = threadIdx.x & 63;
  if (node >= N || lane >= 50) return;
  int b = rowptr[node];
  int deg = rowptr[node + 1] - b;
  int cnt = deg + 1;  // edges then self-loop (last)
  float dn = den[node];
  const float* __restrict__ Hl = HW + 4 * lane;

  auto fS = [&](int t, int &s, float &w) {
    if (t < deg) {
      int2 p = pk[b + t];
      s = p.x;
      w = __fdiv_rn(__int_as_float(p.y), dn);
    } else if (t == deg) {
      s = node;
      w = __fdiv_rn(eeS[node], dn);
    } else {
      s = node;  // cache-hot dummy row
      w = 0.f;
    }
  };

  int sa, sb, sc, sd, se, sf, sn;
  float w0, w1, w2, w3, w4, w5, wn;
  fS(0, sa, w0); fS(1, sb, w1); fS(2, sc, w2); fS(3, sd, w3);
  float4 h0 = GLD(sa), h1 = GLD(sb), h2 = GLD(sc), h3 = GLD(sd);
  fS(4, se, w4);   // index for the row loaded this iteration
  fS(5, sf, w5);   // staged one further

  float4 acc = make_float4(0.f, 0.f, 0.f, 0.f);
  for (int t = 0; t < cnt; t++) {
    float4 h4 = GLD(se);        // row t+4
    fS(t + 6, sn, wn);          // indices for row t+6
    ACC(w0, h0);                // consume row t (loaded 4 iterations ago)
    h0 = h1; h1 = h2; h2 = h3; h3 = h4;
    w0 = w1; w1 = w2; w2 = w3; w3 = w4; w4 = w5; w5 = wn;
    se = sf; sf = sn;
  }

  // fused epi: per element j, exactly old epi_k's ops on the same value
  float4 bv4 = *(const float4*)(bias + 4 * lane);
  float vin[4] = {acc.x, acc.y, acc.z, acc.w};
  float bb4[4] = {bv4.x, bv4.y, bv4.z, bv4.w};
  float vout[4];
  int tbase = node * 200 + 4 * lane;
#pragma unroll
  for (int j = 0; j < 4; j++) {
    uint32_t x0 = 0u, x1 = (uint32_t)(tbase + j);
    threefry2x32(tk0, tk1, x0, x1);
    uint32_t bits = x0 ^ x1;
    float u = __uint_as_float((bits >> 9) | 0x3f800000u) - 1.0f;
    float v = vin[j] + bb4[j];
    v = fmaxf(v, 0.f);
    vout[j] = (u < 0.8f) ? (v / 0.8f) : 0.f;
  }
  *(float4*)(OUT + (size_t)node * 200 + 4 * lane) =
      make_float4(vout[0], vout[1], vout[2], vout[3]);
}

// ---------------- pooling kernels -------------------------------------------
__global__ __launch_bounds__(256) void einit_k(
    const int* __restrict__ src, const int* __restrict__ dst,
    int* __restrict__ cs, int* __restrict__ cd, int* __restrict__ orig,
    int E, int N) {
  int e = blockIdx.x * 256 + threadIdx.x;
  if (e < E) { cs[e] = src[e]; cd[e] = dst[e]; }
  if (e < N) orig[e] = e;
}

// Fused pool_agg + score: agg row stays in the wave (staged through LDS),
// then score2's EXACT summation loop (d = lane; d += 64; shfl_down tree;
// tanhf) runs on it -> bitwise identical score, AGG never hits global.
__global__ __launch_bounds__(256) void pool_agg_k(
    const int* __restrict__ rowptr, const int* __restrict__ csr,
    const int* __restrict__ csrc, const int* __restrict__ orig,
    const float* __restrict__ H, const float* __restrict__ wrel,
    const float* __restrict__ wroot, const float* __restrict__ bp,
    float* __restrict__ score, int n) {
  __shared__ float sagg[4][200];
  int wv = threadIdx.x >> 6;
  int node = blockIdx.x * 4 + wv;
  int lane = threadIdx.x & 63;
  if (node >= n) return;
  int o = orig[node];
  int b = rowptr[o];
  int deg = rowptr[o + 1] - b;

  if (lane < 50) {
    const float* __restrict__ Hl = H + 4 * lane;
    auto fS = [&](int t, int &s, float &w) {
      if (t < deg) {
        int e = csr[b + t];
        int sv = csrc[e];
        s = (sv >= 0) ? sv : 0;
        w = (sv >= 0) ? 1.f : 0.f;
      } else {
        s = 0;
        w = 0.f;
      }
    };

    int sa, sb, sc, sd, se, sf, sn;
    float w0, w1, w2, w3, w4, w5, wn;
    fS(0, sa, w0); fS(1, sb, w1); fS(2, sc, w2); fS(3, sd, w3);
    float4 h0 = GLD(sa), h1 = GLD(sb), h2 = GLD(sc), h3 = GLD(sd);
    fS(4, se, w4);
    fS(5, sf, w5);

    float4 acc = make_float4(0.f, 0.f, 0.f, 0.f);
    for (int t = 0; t < deg; t++) {
      float4 h4 = GLD(se);
      fS(t + 6, sn, wn);
      ACC(w0, h0);
      h0 = h1; h1 = h2; h2 = h3; h3 = h4;
      w0 = w1; w1 = w2; w2 = w3; w3 = w4; w4 = w5; w5 = wn;
      se = sf; sf = sn;
    }
    sagg[wv][4 * lane + 0] = acc.x;
    sagg[wv][4 * lane + 1] = acc.y;
    sagg[wv][4 * lane + 2] = acc.z;
    sagg[wv][4 * lane + 3] = acc.w;
  }
  __threadfence_block();  // order LDS writes before reads (wave-local)

  // score2's exact association: d = lane; d < 200; d += 64, then shfl tree
  const float* arow = sagg[wv];
  const float* hrow = H + (size_t)node * 200;
  float s1 = 0.f, s2 = 0.f;
  for (int d = lane; d < 200; d += 64) {
    s1 += arow[d] * wrel[d];
    s2 += hrow[d] * wroot[d];
  }
  for (int off = 32; off; off >>= 1) {
    s1 += __shfl_down(s1, off);
    s2 += __shfl_down(s2, off);
  }
  if (lane == 0) score[node] = tanhf((s1 + s2) + bp[0]);
}
#undef GLD
#undef ACC

// ---------------- stable LSD radix sort -> exact lax.top_k rank --------------
// Stable ascending sort on ~enc (= descending score, ties by original index
// ascending): sorted position r IS rank[i]. Tie-proof O(n); deterministic.
// -0.0 canonicalized to +0.0 so float equality semantics are preserved.

// pass-0: encode key + write key/pay + histogram digit 0
__global__ __launch_bounds__(256) void rhenc_k(const float* __restrict__ score,
                                               unsigned* __restrict__ keyA,
                                               int* __restrict__ payA,
                                               int* __restrict__ counts,
                                               int n, int NB) {
  __shared__ int hist[256];
  hist[threadIdx.x] = 0;
  __syncthreads();
  int i = blockIdx.x * 256 + threadIdx.x;
  if (i < n) {
    unsigned b = __float_as_uint(score[i]);
    if (b == 0x80000000u) b = 0u;  // -0 -> +0
    unsigned key = ~enc_ord(__uint_as_float(b));
    keyA[i] = key;
    payA[i] = i;
    atomicAdd(&hist[key & 255u], 1);
  }
  __syncthreads();
  counts[threadIdx.x * NB + blockIdx.x] = hist[threadIdx.x];
}

// single block: exclusive scan (digit-major, block-minor) + zero counts
__global__ __launch_bounds__(256) void rscan_k(int* __restrict__ counts,
                                               int* __restrict__ base, int NB) {
  __shared__ int tot[256];
  int t = threadIdx.x;
  int s = 0;
  for (int b = 0; b < NB; b++) s += counts[t * NB + b];
  tot[t] = s;
  __syncthreads();
  if (t == 0) {
    int run = 0;
    for (int i = 0; i < 256; i++) { int v = tot[i]; tot[i] = run; run += v; }
  }
  __syncthreads();
  int run = tot[t];
  for (int b = 0; b < NB; b++) {
    int c = counts[t * NB + b];
    base[t * NB + b] = run;
    run += c;
    counts[t * NB + b] = 0;  // ready for next pass's fused histogram
  }
}

// stable scatter + fused next-pass histogram (atomicAdd keyed by destination
// block: commutative int adds -> deterministic)
__global__ __launch_bounds__(256) void rscatter_k(
    const unsigned* __restrict__ keyIn, const int* __restrict__ payIn,
    const int* __restrict__ base, unsigned* __restrict__ keyOut,
    int* __restrict__ payOut, int* __restrict__ countsNext,
    int n, int NB, int shift) {
  __shared__ int dig[256];
  int t = threadIdx.x;
  int i = blockIdx.x * 256 + t;
  unsigned k = 0u;
  int p = 0, d = -1;
  if (i < n) {
    k = keyIn[i];
    p = payIn[i];
    d = (int)((k >> shift) & 255u);
  }
  dig[t] = d;
  __syncthreads();
  if (i < n) {
    int local = 0;
    for (int j = 0; j < t; j++) local += (dig[j] == d) ? 1 : 0;
    int pos = base[d * NB + blockIdx.x] + local;
    keyOut[pos] = k;
    payOut[pos] = p;
    int nd = (int)((k >> (shift + 8)) & 255u);
    atomicAdd(&countsNext[nd * NB + (pos >> 8)], 1);
  }
}

// final pass (shift=24): scatter position IS the rank -> write perm/inv/oout
__global__ __launch_bounds__(256) void rscatterF_k(
    const unsigned* __restrict__ keyIn, const int* __restrict__ payIn,
    const int* __restrict__ base, const int* __restrict__ oin,
    int* __restrict__ oout, int* __restrict__ perm, int* __restrict__ inv,
    int n, int NB, int k) {
  __shared__ int dig[256];
  int t = threadIdx.x;
  int i = blockIdx.x * 256 + t;
  int p = 0, d = -1;
  if (i < n) {
    p = payIn[i];
    d = (int)((keyIn[i] >> 24) & 255u);
  }
  dig[t] = d;
  __syncthreads();
  if (i < n) {
    int local = 0;
    for (int j = 0; j < t; j++) local += (dig[j] == d) ? 1 : 0;
    int pos = base[d * NB + blockIdx.x] + local;  // final stable-sort rank
    if (pos < k) { perm[pos] = p; inv[p] = pos; oout[pos] = oin[p]; }
    else inv[p] = -1;
  }
}

// single-block full radix for small n (<= 4096): same stable 4x8-bit LSD
// semantics as the multi-kernel chain, one launch. Global key/pay scratch,
// LDS histograms + per-digit running cursors (chunks processed in index
// order -> stability preserved).
__global__ __launch_bounds__(256) void rsmall_k(
    const float* __restrict__ score, const int* __restrict__ oin,
    int* __restrict__ oout, int* __restrict__ perm, int* __restrict__ inv,
    unsigned* __restrict__ keyA, unsigned* __restrict__ keyB,
    int* __restrict__ payA, int* __restrict__ payB, int n, int kk) {
  __shared__ int hist[256];
  __shared__ int basev[256];
  __shared__ int dig[256];
  int t = threadIdx.x;
  for (int i = t; i < n; i += 256) {
    unsigned b = __float_as_uint(score[i]);
    if (b == 0x80000000u) b = 0u;  // -0 -> +0
    keyA[i] = ~enc_ord(__uint_as_float(b));
    payA[i] = i;
  }
  __syncthreads();
  unsigned* ki = keyA; unsigned* ko = keyB;
  int* pi = payA; int* po = payB;
  for (int pass = 0; pass < 4; pass++) {
    int shift = pass * 8;
    hist[t] = 0;
    __syncthreads();
    for (int i = t; i < n; i += 256)
      atomicAdd(&hist[(ki[i] >> shift) & 255u], 1);
    __syncthreads();
    if (t == 0) {
      int run = 0;
      for (int i = 0; i < 256; i++) { int v = hist[i]; basev[i] = run; run += v; }
    }
    __syncthreads();
    int nch = (n + 255) / 256;
    for (int c = 0; c < nch; c++) {
      int i = c * 256 + t;
      unsigned kv = 0u;
      int pv = 0, d = -1;
      if (i < n) { kv = ki[i]; pv = pi[i]; d = (int)((kv >> shift) & 255u); }
      dig[t] = d;
      __syncthreads();
      if (i < n) {
        int local = 0;
        for (int j = 0; j < t; j++) local += (dig[j] == d) ? 1 : 0;
        int pos = basev[d] + local;
        if (pass < 3) {
          ko[pos] = kv;
          po[pos] = pv;
        } else {
          if (pos < kk) { perm[pos] = pv; inv[pv] = pos; oout[pos] = oin[pv]; }
          else inv[pv] = -1;
        }
      }
      __syncthreads();
      hist[t] = 0;
      __syncthreads();
      if (i < n) atomicAdd(&hist[d], 1);
      __syncthreads();
      basev[t] += hist[t];
      __syncthreads();
    }
    unsigned* tk = ki; ki = ko; ko = tk;
    int* tp = pi; pi = po; po = tp;
  }
}

__global__ __launch_bounds__(256) void gather_k(
    const float* __restrict__ H, const int* __restrict__ perm,
    const float* __restrict__ score, float* __restrict__ Ho, int k) {
  int r = blockIdx.x;
  int d = threadIdx.x;
  int p = perm[r];
  float s = score[p];
  if (d < 200) Ho[(size_t)r * 200 + d] = __fmul_rn(H[(size_t)p * 200 + d], s);
}

__global__ __launch_bounds__(256) void remap_k(int* __restrict__ cs,
                                               int* __restrict__ cd,
                                               const int* __restrict__ inv, int E) {
  int e = blockIdx.x * 256 + threadIdx.x;
  if (e >= E) return;
  int a = cs[e];
  if (a < 0) return;  // already invalid, stays invalid
  int na = inv[a], nb = inv[cd[e]];
  bool valid = (na >= 0) && (nb >= 0);
  cs[e] = valid ? na : -1;
  cd[e] = valid ? nb : -1;
}

__global__ __launch_bounds__(256) void out_copy_k(const float* __restrict__ h,
                                                  float* __restrict__ out, int cnt) {
  int t = blockIdx.x * 256 + threadIdx.x;
  if (t < cnt) out[t] = h[t];
}

// ---------------------------------------------------------------------------
extern "C" void kernel_launch(void* const* d_in, const int* in_sizes, int n_in,
                              void* d_out, int out_size, void* d_ws, size_t ws_size,
                              hipStream_t stream) {
  const int ID = 128, HD = 200;
  const int N = in_sizes[0] / ID;   // 50000
  const int E = in_sizes[1];        // 800000
  const int total = N * HD;         // 10,000,000

  const float* x = (const float*)d_in[0];
  const int* src = (const int*)d_in[1];
  const int* dst = (const int*)d_in[2];
  const float* W[3]   = {(const float*)d_in[3], (const float*)d_in[7], (const float*)d_in[11]};
  const float* asv[3] = {(const float*)d_in[4], (const float*)d_in[8], (const float*)d_in[12]};
  const float* adv[3] = {(const float*)d_in[5], (const float*)d_in[9], (const float*)d_in[13]};
  const float* bv[3]  = {(const float*)d_in[6], (const float*)d_in[10], (const float*)d_in[14]};
  const float* Wrel  = (const float*)d_in[15];
  const float* Wroot = (const float*)d_in[16];
  const float* bpool = (const float*)d_in[17];

  char* ws = (char*)d_ws;
  float*    bufA  = (float*)(ws + 0);           // 40,000,000
  float*    bufB  = (float*)(ws + 40000000);    // 40,000,000
  float*    as_   = (float*)(ws + 80000000);    //   200,000
  float*    ad_   = (float*)(ws + 80200000);    //   200,000
  // ee_ region (3.4MB): GAT phase -> eeS; pooling phase -> radix scratch
  float*    den   = (float*)(ws + 84000000);    //   200,000
  float*    score = (float*)(ws + 84200000);    //   200,000
  int*      rank_ = (int*)(ws + 84400000);      //   200,000 (CSR count scratch)
  int*      perm_ = (int*)(ws + 84600000);      //   200,000
  int*      inv_  = (int*)(ws + 84800000);      //   200,000
  int*      origA = (int*)(ws + 85000000);      //   200,000
  int*      origB = (int*)(ws + 85200000);      //   200,000
  int*      rowptr= (int*)(ws + 85400000);      //   250,000 (N+1 ints)
  int*      curs  = (int*)(ws + 85650000);      //   200,000
  int*      csr   = (int*)(ws + 85850000);      // 3,200,000
  int*      csrc  = (int*)(ws + 89050000);      // 3,200,000
  int*      cdst  = (int*)(ws + 92250000);      // 3,200,000  -> total 95.45 MB

  // GAT-phase pk array (E x int2 = 6.4 MB) reuses csrc+cdst (written only by
  // einit_k AFTER all GAT layers complete).
  int2* pk = (int2*)(ws + 89050000);
  float* eeS = (float*)(ws + 80400000);  // ee_ region (radix reuses it later)

  // Radix scratch reuses the GAT-only ee_ region (free during pooling):
  char* rx = ws + 80400000;
  unsigned* keyA   = (unsigned*)(rx + 0 * 262144);
  unsigned* keyB   = (unsigned*)(rx + 1 * 262144);
  int*      payA   = (int*)(rx + 2 * 262144);
  int*      payB   = (int*)(rx + 3 * 262144);
  int*      rcounts= (int*)(rx + 4 * 262144);
  int*      rbase  = (int*)(rx + 5 * 262144);

  // Host-side fold_in(key(42), i) = threefry2x32(k=(0,42), x=(0,i)).
  uint32_t fk0[3], fk1[3];
  for (int i = 0; i < 3; i++) {
    uint32_t a = 0u, b = (uint32_t)i;
    threefry2x32(0u, 42u, a, b);
    fk0[i] = a; fk1[i] = b;
  }

  const int B256 = 256;
  // ---------------- CSR build (once) ----------------
  hipMemsetAsync(rank_, 0, (size_t)N * 4, stream);
  indeg_k<<<(E + 255) / 256, B256, 0, stream>>>(dst, rank_, E);
  scan_k<<<1, B256, 0, stream>>>(rank_, rowptr, N);
  cpyint_k<<<(N + 255) / 256, B256, 0, stream>>>(rowptr, curs, N);
  place_k<<<(E + 255) / 256, B256, 0, stream>>>(dst, curs, csr, E);
  sortrow_k<<<(N + 255) / 256, B256, 0, stream>>>(rowptr, csr, N);

  // ---------------- 3 GAT layers ----------------
  for (int i = 0; i < 3; i++) {
    const float* in = (i == 0) ? x : bufB;
    int K = (i == 0) ? ID : HD;
    gemm200_k<<<(N + 127) / 128, B256, 0, stream>>>(in, W[i], bufA, N, K);
    dual_dot_k<<<(N + 3) / 4, B256, 0, stream>>>(bufA, asv[i], adv[i], as_, ad_, N);
    eeden_k<<<(N + 255) / 256, B256, 0, stream>>>(rowptr, csr, src, as_, ad_,
                                                  pk, eeS, den, N);
    gat_out_k<<<(N + 3) / 4, B256, 0, stream>>>(rowptr, pk, eeS, den, bufA,
                                                bv[i], bufB, fk0[i], fk1[i], N);
  }

  // ---------------- SAGPooling loop ----------------
  einit_k<<<(E + 255) / 256, B256, 0, stream>>>(src, dst, csrc, cdst, origA, E, N);
  float* hcur = bufB;
  float* hnext = bufA;
  int* ocur = origA;
  int* onext = origB;
  int n = N;
  while (true) {
    int k = (n + 1) / 2;  // ceil(0.5 n)
    int NB = (n + 255) / 256;
    pool_agg_k<<<(n + 3) / 4, B256, 0, stream>>>(rowptr, csr, csrc, ocur, hcur,
                                                 Wrel, Wroot, bpool, score, n);
    if (n <= 4096) {
      // single-block stable radix (1 launch, same semantics)
      rsmall_k<<<1, B256, 0, stream>>>(score, ocur, onext, perm_, inv_,
                                       keyA, keyB, payA, payB, n, k);
    } else {
      rhenc_k<<<NB, B256, 0, stream>>>(score, keyA, payA, rcounts, n, NB);
      rscan_k<<<1, B256, 0, stream>>>(rcounts, rbase, NB);
      rscatter_k<<<NB, B256, 0, stream>>>(keyA, payA, rbase, keyB, payB, rcounts, n, NB, 0);
      rscan_k<<<1, B256, 0, stream>>>(rcounts, rbase, NB);
      rscatter_k<<<NB, B256, 0, stream>>>(keyB, payB, rbase, keyA, payA, rcounts, n, NB, 8);
      rscan_k<<<1, B256, 0, stream>>>(rcounts, rbase, NB);
      rscatter_k<<<NB, B256, 0, stream>>>(keyA, payA, rbase, keyB, payB, rcounts, n, NB, 16);
      rscan_k<<<1, B256, 0, stream>>>(rcounts, rbase, NB);
      rscatterF_k<<<NB, B256, 0, stream>>>(keyB, payB, rbase, ocur, onext, perm_, inv_,
                                           n, NB, k);
    }
    gather_k<<<k, B256, 0, stream>>>(hcur, perm_, score, hnext, k);
    remap_k<<<(E + 255) / 256, B256, 0, stream>>>(csrc, cdst, inv_, E);
    { float* t = hcur; hcur = hnext; hnext = t; }
    { int* t = ocur; ocur = onext; onext = t; }
    n = k;
    if (n <= 512) break;
  }

  // ---------------- output: zeros(512,200) with first n rows = h -------------
  hipMemsetAsync(d_out, 0, (size_t)out_size * 4, stream);
  out_copy_k<<<(n * HD + 255) / 256, B256, 0, stream>>>(hcur, (float*)d_out, n * HD);
}

// Round 9
// 2698.531 us; speedup vs baseline: 1.2180x; 1.2180x over previous
//
#include <hip/hip_runtime.h>
#include <cstdint>
#include <cstddef>

// ---------------------------------------------------------------------------
// GAT x3 (exact JAX-threefry dropout, PARTITIONABLE mode) + SAGPool x7.
// Round 13 = Round 12 minus rsmall_k (post-mortem: single-block radix ran on
// 1 CU with a serial rank loop -> ~420us/launch, masking the ~750us won by
// the epi/edge_max fusions). Multi-kernel radix chain restored for ALL n.
//  * epi_k fused into gat_out_k epilogue (bitwise: same formula, same
//    threefry counter t = node*200+col).
//  * edge_max_k + menc memset fused into eeden_k (integer max over same
//    encoded values -> bit-identical m).
//  * pk pack: gat_out does ONE contiguous 8B load per edge.
//  * pool_agg_k absorbs score2_k (exact summation order + shfl tree).
//  * depth-4 rolling pipelines; gemm float4 epilogue + prefetch + As pad.
// All segment ops remain deterministic + np-association-matched (CSR serial).
// ---------------------------------------------------------------------------

__host__ __device__ inline void tf_round(uint32_t &x0, uint32_t &x1, int r) {
  x0 += x1;
  x1 = (x1 << r) | (x1 >> (32 - r));
  x1 ^= x0;
}

// Exact jax threefry2x32 (Random123 KAT: key(0,0),ctr(0,0) -> 6b200159 99ba4efe)
__host__ __device__ inline void threefry2x32(uint32_t k0, uint32_t k1,
                                             uint32_t &x0, uint32_t &x1) {
  uint32_t ks2 = k0 ^ k1 ^ 0x1BD11BDAu;
  x0 += k0; x1 += k1;
  tf_round(x0, x1, 13); tf_round(x0, x1, 15); tf_round(x0, x1, 26); tf_round(x0, x1, 6);
  x0 += k1; x1 += ks2 + 1u;
  tf_round(x0, x1, 17); tf_round(x0, x1, 29); tf_round(x0, x1, 16); tf_round(x0, x1, 24);
  x0 += ks2; x1 += k0 + 2u;
  tf_round(x0, x1, 13); tf_round(x0, x1, 15); tf_round(x0, x1, 26); tf_round(x0, x1, 6);
  x0 += k0; x1 += k1 + 3u;
  tf_round(x0, x1, 17); tf_round(x0, x1, 29); tf_round(x0, x1, 16); tf_round(x0, x1, 24);
  x0 += k1; x1 += ks2 + 4u;
  tf_round(x0, x1, 13); tf_round(x0, x1, 15); tf_round(x0, x1, 26); tf_round(x0, x1, 6);
  x0 += ks2; x1 += k0 + 5u;
}

// ---------------- GEMM: C[M x 200] = A[M x K] @ B[K x 200], fp32 -------------
__global__ __launch_bounds__(256) void gemm200_k(
    const float* __restrict__ A, const float* __restrict__ B,
    float* __restrict__ C, int M, int K) {
  __shared__ float As[128 * 9];                 // pad 8->9: conflict-free reads
  __shared__ __align__(16) float Bs[8][208];
  int tid = threadIdx.x;
  int m0 = blockIdx.x * 128;
  int r = tid >> 2;
  int colBase = (tid & 3) * 52;
  int nq = (colBase == 156) ? 11 : 13;          // valid float4s in epilogue
  float acc0[52], acc1[52];
#pragma unroll
  for (int q = 0; q < 52; q++) { acc0[q] = 0.f; acc1[q] = 0.f; }

  // staging assignments
  int arow = tid >> 1;
  int ac = (tid & 1) * 4;
  int gmA = m0 + arow;
  const float* Aptr = A + (size_t)gmA * K + ac;
  int bk0 = tid / 50, bc0 = (tid - bk0 * 50) * 4;
  int t2 = tid + 256;
  int bk1 = t2 / 50, bc1 = (t2 - bk1 * 50) * 4;
  bool hasB1 = (t2 < 400);

  // prefetch tile 0 into registers
  float4 va = make_float4(0.f, 0.f, 0.f, 0.f);
  if (gmA < M) va = *(const float4*)(Aptr);
  float4 vb0 = *(const float4*)(B + (size_t)bk0 * 200 + bc0);
  float4 vb1 = make_float4(0.f, 0.f, 0.f, 0.f);
  if (hasB1) vb1 = *(const float4*)(B + (size_t)bk1 * 200 + bc1);

  for (int k0 = 0; k0 < K; k0 += 8) {
    // commit staged registers to LDS
    As[arow * 9 + ac + 0] = va.x;
    As[arow * 9 + ac + 1] = va.y;
    As[arow * 9 + ac + 2] = va.z;
    As[arow * 9 + ac + 3] = va.w;
    *(float4*)(&Bs[bk0][bc0]) = vb0;
    if (hasB1) *(float4*)(&Bs[bk1][bc1]) = vb1;
    __syncthreads();
    // issue next-tile global loads; they land under the FMA phase below
    int kn = k0 + 8;
    if (kn < K) {
      if (gmA < M) va = *(const float4*)(Aptr + kn);
      vb0 = *(const float4*)(B + (size_t)(kn + bk0) * 200 + bc0);
      if (hasB1) vb1 = *(const float4*)(B + (size_t)(kn + bk1) * 200 + bc1);
    }
#pragma unroll
    for (int kk = 0; kk < 8; kk++) {
      float a0 = As[r * 9 + kk];
      float a1 = As[(r + 64) * 9 + kk];
#pragma unroll
      for (int q = 0; q < 13; q++) {
        float4 b = *(const float4*)(&Bs[kk][colBase + 4 * q]);
        acc0[4 * q + 0] += a0 * b.x; acc0[4 * q + 1] += a0 * b.y;
        acc0[4 * q + 2] += a0 * b.z; acc0[4 * q + 3] += a0 * b.w;
        acc1[4 * q + 0] += a1 * b.x; acc1[4 * q + 1] += a1 * b.y;
        acc1[4 * q + 2] += a1 * b.z; acc1[4 * q + 3] += a1 * b.w;
      }
    }
    __syncthreads();
  }
  // epilogue: coalesced float4 stores
  int gm0 = m0 + r, gm1 = m0 + r + 64;
#pragma unroll
  for (int q = 0; q < 13; q++) {
    if (q < nq) {
      int col = colBase + 4 * q;
      float4 v0 = make_float4(acc0[4 * q + 0], acc0[4 * q + 1],
                              acc0[4 * q + 2], acc0[4 * q + 3]);
      float4 v1 = make_float4(acc1[4 * q + 0], acc1[4 * q + 1],
                              acc1[4 * q + 2], acc1[4 * q + 3]);
      if (gm0 < M) *(float4*)(C + (size_t)gm0 * 200 + col) = v0;
      if (gm1 < M) *(float4*)(C + (size_t)gm1 * 200 + col) = v1;
    }
  }
}

// ---------------- dual dot: o1[i]=H[i]·v1, o2[i]=H[i]·v2 (one wave/node) -----
__global__ __launch_bounds__(256) void dual_dot_k(
    const float* __restrict__ H, const float* __restrict__ v1,
    const float* __restrict__ v2, float* __restrict__ o1,
    float* __restrict__ o2, int n) {
  int wave = blockIdx.x * 4 + (threadIdx.x >> 6);
  int lane = threadIdx.x & 63;
  if (wave >= n) return;
  const float* row = H + (size_t)wave * 200;
  float s1 = 0.f, s2 = 0.f;
  for (int d = lane; d < 200; d += 64) {
    float h = row[d];
    s1 += h * v1[d];
    s2 += h * v2[d];
  }
  for (int off = 32; off; off >>= 1) {
    s1 += __shfl_down(s1, off);
    s2 += __shfl_down(s2, off);
  }
  if (lane == 0) { o1[wave] = s1; o2[wave] = s2; }
}

// ---------------- CSR build (dst-sorted, stable by edge index) ---------------
__global__ __launch_bounds__(256) void indeg_k(const int* __restrict__ dst,
                                               int* __restrict__ cnt, int E) {
  int e = blockIdx.x * 256 + threadIdx.x;
  if (e < E) atomicAdd(&cnt[dst[e]], 1);
}

// single block, 256 threads: exclusive scan cnt[0..N) -> rowptr[0..N]
__global__ __launch_bounds__(256) void scan_k(const int* __restrict__ cnt,
                                              int* __restrict__ rowptr, int N) {
  __shared__ int psum[256];
  int t = threadIdx.x;
  int CH = (N + 255) / 256;
  int beg = t * CH, end = min(beg + CH, N);
  if (beg > N) { beg = N; }
  int s = 0;
  for (int i = beg; i < end; i++) s += cnt[i];
  psum[t] = s;
  __syncthreads();
  if (t == 0) {
    int run = 0;
    for (int i = 0; i < 256; i++) { int v = psum[i]; psum[i] = run; run += v; }
  }
  __syncthreads();
  int run = psum[t];
  for (int i = beg; i < end; i++) { rowptr[i] = run; run += cnt[i]; }
  if (end == N && beg <= N) rowptr[N] = run;
}

__global__ __launch_bounds__(256) void cpyint_k(const int* __restrict__ a,
                                                int* __restrict__ b, int n) {
  int i = blockIdx.x * 256 + threadIdx.x;
  if (i < n) b[i] = a[i];
}

__global__ __launch_bounds__(256) void place_k(const int* __restrict__ dst,
                                               int* __restrict__ curs,
                                               int* __restrict__ csr, int E) {
  int e = blockIdx.x * 256 + threadIdx.x;
  if (e >= E) return;
  int pos = atomicAdd(&curs[dst[e]], 1);
  csr[pos] = e;
}

__global__ __launch_bounds__(256) void sortrow_k(const int* __restrict__ rowptr,
                                                 int* __restrict__ csr, int N) {
  int d = blockIdx.x * 256 + threadIdx.x;
  if (d >= N) return;
  int b = rowptr[d], e2 = rowptr[d + 1];
  for (int i = b + 1; i < e2; i++) {
    int v = csr[i];
    int j = i - 1;
    while (j >= b && csr[j] > v) { csr[j + 1] = csr[j]; j--; }
    csr[j + 1] = v;
  }
}

// ---------------- GAT edge softmax (deterministic, np order) -----------------
__device__ inline float dec_ord(unsigned enc) {
  unsigned b = (enc & 0x80000000u) ? (enc ^ 0x80000000u) : ~enc;
  return __uint_as_float(b);
}

__device__ inline unsigned enc_ord(float ev) {
  unsigned b = __float_as_uint(ev);
  return (b & 0x80000000u) ? ~b : (b | 0x80000000u);
}

// Fused max + ee + den + CSR-position pack: one thread per node d, serial
// over its CSR row. Pass 1: integer max of order-encoded leaky values over
// {row edges} U {self} -- identical result to the old memset(0)+atomicMax
// (max is commutative/idempotent on the encoding; enc > 0 always so the 0
// init never wins). Pass 2: ee/pk/den in EXACT old ee_k/den_k order (serial
// __fadd_rn, self-loop last) -> bitwise identical.
__global__ __launch_bounds__(256) void eeden_k(
    const int* __restrict__ rowptr, const int* __restrict__ csr,
    const int* __restrict__ src, const float* __restrict__ as_,
    const float* __restrict__ ad_, int2* __restrict__ pk,
    float* __restrict__ eeS, float* __restrict__ den, int N) {
  int d = blockIdx.x * 256 + threadIdx.x;
  if (d >= N) return;
  float adv = ad_[d];
  int b = rowptr[d], e2 = rowptr[d + 1];
  unsigned mx = 0u;
  for (int i = b; i < e2; i++) {
    int sv = src[csr[i]];
    float v = as_[sv] + adv;
    float ev = (v >= 0.f) ? v : 0.2f * v;
    mx = max(mx, enc_ord(ev));
  }
  {
    float v = as_[d] + adv;  // self-loop term
    float ev = (v >= 0.f) ? v : 0.2f * v;
    mx = max(mx, enc_ord(ev));
  }
  float m = dec_ord(mx);
  float s = 0.f;
  for (int i = b; i < e2; i++) {
    int sv = src[csr[i]];
    float v = as_[sv] + adv;
    float ev = (v >= 0.f) ? v : 0.2f * v;
    float ee = expf(ev - m);
    pk[i] = make_int2(sv, __float_as_int(ee));
    s = __fadd_rn(s, ee);
  }
  float vS = as_[d] + adv;
  float evS = (vS >= 0.f) ? vS : 0.2f * vS;
  float eS = expf(evS - m);
  eeS[d] = eS;
  s = __fadd_rn(s, eS);
  den[d] = s;
}

#define GLD(s) (*(const float4*)(Hl + (size_t)(s) * 200))
#define ACC(W_, H_)                                    \
  acc.x = __fadd_rn(acc.x, __fmul_rn((W_), (H_).x));   \
  acc.y = __fadd_rn(acc.y, __fmul_rn((W_), (H_).y));   \
  acc.z = __fadd_rn(acc.z, __fmul_rn((W_), (H_).z));   \
  acc.w = __fadd_rn(acc.w, __fmul_rn((W_), (H_).w));

// GAT out + fused epilogue (bias/relu/threefry-dropout, bitwise = old epi_k
// on the identical just-computed value; threefry counter t = node*200+col).
// Wave per node, serial over edges (edge-index order, self last). Depth-4
// rolling pipeline; per edge ONE contiguous 8B pk load. w = __fdiv_rn(ee,den)
// is bitwise alpha_k's division. Pad slots read the node's own cache-hot row
// with w=0 -> exact FP no-ops.
__global__ __launch_bounds__(256) void gat_out_k(
    const int* __restrict__ rowptr, const int2* __restrict__ pk,
    const float* __restrict__ eeS, const float* __restrict__ den,
    const float* __restrict__ HW, const float* __restrict__ bias,
    float* __restrict__ OUT, uint32_t tk0, uint32_t tk1, int N) {
  int node = blockIdx.x * 4 + (threadIdx.x >> 6);
  int lane = threadIdx.x & 63;
  if (node >= N || lane >= 50) return;
  int b = rowptr[node];
  int deg = rowptr[node + 1] - b;
  int cnt = deg + 1;  // edges then self-loop (last)
  float dn = den[node];
  const float* __restrict__ Hl = HW + 4 * lane;

  auto fS = [&](int t, int &s, float &w) {
    if (t < deg) {
      int2 p = pk[b + t];
      s = p.x;
      w = __fdiv_rn(__int_as_float(p.y), dn);
    } else if (t == deg) {
      s = node;
      w = __fdiv_rn(eeS[node], dn);
    } else {
      s = node;  // cache-hot dummy row
      w = 0.f;
    }
  };

  int sa, sb, sc, sd, se, sf, sn;
  float w0, w1, w2, w3, w4, w5, wn;
  fS(0, sa, w0); fS(1, sb, w1); fS(2, sc, w2); fS(3, sd, w3);
  float4 h0 = GLD(sa), h1 = GLD(sb), h2 = GLD(sc), h3 = GLD(sd);
  fS(4, se, w4);   // index for the row loaded this iteration
  fS(5, sf, w5);   // staged one further

  float4 acc = make_float4(0.f, 0.f, 0.f, 0.f);
  for (int t = 0; t < cnt; t++) {
    float4 h4 = GLD(se);        // row t+4
    fS(t + 6, sn, wn);          // indices for row t+6
    ACC(w0, h0);                // consume row t (loaded 4 iterations ago)
    h0 = h1; h1 = h2; h2 = h3; h3 = h4;
    w0 = w1; w1 = w2; w2 = w3; w3 = w4; w4 = w5; w5 = wn;
    se = sf; sf = sn;
  }

  // fused epi: per element j, exactly old epi_k's ops on the same value
  float4 bv4 = *(const float4*)(bias + 4 * lane);
  float vin[4] = {acc.x, acc.y, acc.z, acc.w};
  float bb4[4] = {bv4.x, bv4.y, bv4.z, bv4.w};
  float vout[4];
  int tbase = node * 200 + 4 * lane;
#pragma unroll
  for (int j = 0; j < 4; j++) {
    uint32_t x0 = 0u, x1 = (uint32_t)(tbase + j);
    threefry2x32(tk0, tk1, x0, x1);
    uint32_t bits = x0 ^ x1;
    float u = __uint_as_float((bits >> 9) | 0x3f800000u) - 1.0f;
    float v = vin[j] + bb4[j];
    v = fmaxf(v, 0.f);
    vout[j] = (u < 0.8f) ? (v / 0.8f) : 0.f;
  }
  *(float4*)(OUT + (size_t)node * 200 + 4 * lane) =
      make_float4(vout[0], vout[1], vout[2], vout[3]);
}

// ---------------- pooling kernels -------------------------------------------
__global__ __launch_bounds__(256) void einit_k(
    const int* __restrict__ src, const int* __restrict__ dst,
    int* __restrict__ cs, int* __restrict__ cd, int* __restrict__ orig,
    int E, int N) {
  int e = blockIdx.x * 256 + threadIdx.x;
  if (e < E) { cs[e] = src[e]; cd[e] = dst[e]; }
  if (e < N) orig[e] = e;
}

// Fused pool_agg + score: agg row stays in the wave (staged through LDS),
// then score2's EXACT summation loop (d = lane; d += 64; shfl_down tree;
// tanhf) runs on it -> bitwise identical score, AGG never hits global.
__global__ __launch_bounds__(256) void pool_agg_k(
    const int* __restrict__ rowptr, const int* __restrict__ csr,
    const int* __restrict__ csrc, const int* __restrict__ orig,
    const float* __restrict__ H, const float* __restrict__ wrel,
    const float* __restrict__ wroot, const float* __restrict__ bp,
    float* __restrict__ score, int n) {
  __shared__ float sagg[4][200];
  int wv = threadIdx.x >> 6;
  int node = blockIdx.x * 4 + wv;
  int lane = threadIdx.x & 63;
  if (node >= n) return;
  int o = orig[node];
  int b = rowptr[o];
  int deg = rowptr[o + 1] - b;

  if (lane < 50) {
    const float* __restrict__ Hl = H + 4 * lane;
    auto fS = [&](int t, int &s, float &w) {
      if (t < deg) {
        int e = csr[b + t];
        int sv = csrc[e];
        s = (sv >= 0) ? sv : 0;
        w = (sv >= 0) ? 1.f : 0.f;
      } else {
        s = 0;
        w = 0.f;
      }
    };

    int sa, sb, sc, sd, se, sf, sn;
    float w0, w1, w2, w3, w4, w5, wn;
    fS(0, sa, w0); fS(1, sb, w1); fS(2, sc, w2); fS(3, sd, w3);
    float4 h0 = GLD(sa), h1 = GLD(sb), h2 = GLD(sc), h3 = GLD(sd);
    fS(4, se, w4);
    fS(5, sf, w5);

    float4 acc = make_float4(0.f, 0.f, 0.f, 0.f);
    for (int t = 0; t < deg; t++) {
      float4 h4 = GLD(se);
      fS(t + 6, sn, wn);
      ACC(w0, h0);
      h0 = h1; h1 = h2; h2 = h3; h3 = h4;
      w0 = w1; w1 = w2; w2 = w3; w3 = w4; w4 = w5; w5 = wn;
      se = sf; sf = sn;
    }
    sagg[wv][4 * lane + 0] = acc.x;
    sagg[wv][4 * lane + 1] = acc.y;
    sagg[wv][4 * lane + 2] = acc.z;
    sagg[wv][4 * lane + 3] = acc.w;
  }
  __threadfence_block();  // order LDS writes before reads (wave-local)

  // score2's exact association: d = lane; d < 200; d += 64, then shfl tree
  const float* arow = sagg[wv];
  const float* hrow = H + (size_t)node * 200;
  float s1 = 0.f, s2 = 0.f;
  for (int d = lane; d < 200; d += 64) {
    s1 += arow[d] * wrel[d];
    s2 += hrow[d] * wroot[d];
  }
  for (int off = 32; off; off >>= 1) {
    s1 += __shfl_down(s1, off);
    s2 += __shfl_down(s2, off);
  }
  if (lane == 0) score[node] = tanhf((s1 + s2) + bp[0]);
}
#undef GLD
#undef ACC

// ---------------- stable LSD radix sort -> exact lax.top_k rank --------------
// Stable ascending sort on ~enc (= descending score, ties by original index
// ascending): sorted position r IS rank[i]. Tie-proof O(n); deterministic.
// -0.0 canonicalized to +0.0 so float equality semantics are preserved.

// pass-0: encode key + write key/pay + histogram digit 0
__global__ __launch_bounds__(256) void rhenc_k(const float* __restrict__ score,
                                               unsigned* __restrict__ keyA,
                                               int* __restrict__ payA,
                                               int* __restrict__ counts,
                                               int n, int NB) {
  __shared__ int hist[256];
  hist[threadIdx.x] = 0;
  __syncthreads();
  int i = blockIdx.x * 256 + threadIdx.x;
  if (i < n) {
    unsigned b = __float_as_uint(score[i]);
    if (b == 0x80000000u) b = 0u;  // -0 -> +0
    unsigned key = ~enc_ord(__uint_as_float(b));
    keyA[i] = key;
    payA[i] = i;
    atomicAdd(&hist[key & 255u], 1);
  }
  __syncthreads();
  counts[threadIdx.x * NB + blockIdx.x] = hist[threadIdx.x];
}

// single block: exclusive scan (digit-major, block-minor) + zero counts
__global__ __launch_bounds__(256) void rscan_k(int* __restrict__ counts,
                                               int* __restrict__ base, int NB) {
  __shared__ int tot[256];
  int t = threadIdx.x;
  int s = 0;
  for (int b = 0; b < NB; b++) s += counts[t * NB + b];
  tot[t] = s;
  __syncthreads();
  if (t == 0) {
    int run = 0;
    for (int i = 0; i < 256; i++) { int v = tot[i]; tot[i] = run; run += v; }
  }
  __syncthreads();
  int run = tot[t];
  for (int b = 0; b < NB; b++) {
    int c = counts[t * NB + b];
    base[t * NB + b] = run;
    run += c;
    counts[t * NB + b] = 0;  // ready for next pass's fused histogram
  }
}

// stable scatter + fused next-pass histogram (atomicAdd keyed by destination
// block: commutative int adds -> deterministic)
__global__ __launch_bounds__(256) void rscatter_k(
    const unsigned* __restrict__ keyIn, const int* __restrict__ payIn,
    const int* __restrict__ base, unsigned* __restrict__ keyOut,
    int* __restrict__ payOut, int* __restrict__ countsNext,
    int n, int NB, int shift) {
  __shared__ int dig[256];
  int t = threadIdx.x;
  int i = blockIdx.x * 256 + t;
  unsigned k = 0u;
  int p = 0, d = -1;
  if (i < n) {
    k = keyIn[i];
    p = payIn[i];
    d = (int)((k >> shift) & 255u);
  }
  dig[t] = d;
  __syncthreads();
  if (i < n) {
    int local = 0;
    for (int j = 0; j < t; j++) local += (dig[j] == d) ? 1 : 0;
    int pos = base[d * NB + blockIdx.x] + local;
    keyOut[pos] = k;
    payOut[pos] = p;
    int nd = (int)((k >> (shift + 8)) & 255u);
    atomicAdd(&countsNext[nd * NB + (pos >> 8)], 1);
  }
}

// final pass (shift=24): scatter position IS the rank -> write perm/inv/oout
__global__ __launch_bounds__(256) void rscatterF_k(
    const unsigned* __restrict__ keyIn, const int* __restrict__ payIn,
    const int* __restrict__ base, const int* __restrict__ oin,
    int* __restrict__ oout, int* __restrict__ perm, int* __restrict__ inv,
    int n, int NB, int k) {
  __shared__ int dig[256];
  int t = threadIdx.x;
  int i = blockIdx.x * 256 + t;
  int p = 0, d = -1;
  if (i < n) {
    p = payIn[i];
    d = (int)((keyIn[i] >> 24) & 255u);
  }
  dig[t] = d;
  __syncthreads();
  if (i < n) {
    int local = 0;
    for (int j = 0; j < t; j++) local += (dig[j] == d) ? 1 : 0;
    int pos = base[d * NB + blockIdx.x] + local;  // final stable-sort rank
    if (pos < k) { perm[pos] = p; inv[p] = pos; oout[pos] = oin[p]; }
    else inv[p] = -1;
  }
}

__global__ __launch_bounds__(256) void gather_k(
    const float* __restrict__ H, const int* __restrict__ perm,
    const float* __restrict__ score, float* __restrict__ Ho, int k) {
  int r = blockIdx.x;
  int d = threadIdx.x;
  int p = perm[r];
  float s = score[p];
  if (d < 200) Ho[(size_t)r * 200 + d] = __fmul_rn(H[(size_t)p * 200 + d], s);
}

__global__ __launch_bounds__(256) void remap_k(int* __restrict__ cs,
                                               int* __restrict__ cd,
                                               const int* __restrict__ inv, int E) {
  int e = blockIdx.x * 256 + threadIdx.x;
  if (e >= E) return;
  int a = cs[e];
  if (a < 0) return;  // already invalid, stays invalid
  int na = inv[a], nb = inv[cd[e]];
  bool valid = (na >= 0) && (nb >= 0);
  cs[e] = valid ? na : -1;
  cd[e] = valid ? nb : -1;
}

__global__ __launch_bounds__(256) void out_copy_k(const float* __restrict__ h,
                                                  float* __restrict__ out, int cnt) {
  int t = blockIdx.x * 256 + threadIdx.x;
  if (t < cnt) out[t] = h[t];
}

// ---------------------------------------------------------------------------
extern "C" void kernel_launch(void* const* d_in, const int* in_sizes, int n_in,
                              void* d_out, int out_size, void* d_ws, size_t ws_size,
                              hipStream_t stream) {
  const int ID = 128, HD = 200;
  const int N = in_sizes[0] / ID;   // 50000
  const int E = in_sizes[1];        // 800000

  const float* x = (const float*)d_in[0];
  const int* src = (const int*)d_in[1];
  const int* dst = (const int*)d_in[2];
  const float* W[3]   = {(const float*)d_in[3], (const float*)d_in[7], (const float*)d_in[11]};
  const float* asv[3] = {(const float*)d_in[4], (const float*)d_in[8], (const float*)d_in[12]};
  const float* adv[3] = {(const float*)d_in[5], (const float*)d_in[9], (const float*)d_in[13]};
  const float* bv[3]  = {(const float*)d_in[6], (const float*)d_in[10], (const float*)d_in[14]};
  const float* Wrel  = (const float*)d_in[15];
  const float* Wroot = (const float*)d_in[16];
  const float* bpool = (const float*)d_in[17];

  char* ws = (char*)d_ws;
  float*    bufA  = (float*)(ws + 0);           // 40,000,000
  float*    bufB  = (float*)(ws + 40000000);    // 40,000,000
  float*    as_   = (float*)(ws + 80000000);    //   200,000
  float*    ad_   = (float*)(ws + 80200000);    //   200,000
  // ee_ region (3.4MB): GAT phase -> eeS; pooling phase -> radix scratch
  float*    den   = (float*)(ws + 84000000);    //   200,000
  float*    score = (float*)(ws + 84200000);    //   200,000
  int*      rank_ = (int*)(ws + 84400000);      //   200,000 (CSR count scratch)
  int*      perm_ = (int*)(ws + 84600000);      //   200,000
  int*      inv_  = (int*)(ws + 84800000);      //   200,000
  int*      origA = (int*)(ws + 85000000);      //   200,000
  int*      origB = (int*)(ws + 85200000);      //   200,000
  int*      rowptr= (int*)(ws + 85400000);      //   250,000 (N+1 ints)
  int*      curs  = (int*)(ws + 85650000);      //   200,000
  int*      csr   = (int*)(ws + 85850000);      // 3,200,000
  int*      csrc  = (int*)(ws + 89050000);      // 3,200,000
  int*      cdst  = (int*)(ws + 92250000);      // 3,200,000  -> total 95.45 MB

  // GAT-phase pk array (E x int2 = 6.4 MB) reuses csrc+cdst (written only by
  // einit_k AFTER all GAT layers complete).
  int2* pk = (int2*)(ws + 89050000);
  float* eeS = (float*)(ws + 80400000);  // ee_ region (radix reuses it later)

  // Radix scratch reuses the GAT-only ee_ region (free during pooling):
  char* rx = ws + 80400000;
  unsigned* keyA   = (unsigned*)(rx + 0 * 262144);
  unsigned* keyB   = (unsigned*)(rx + 1 * 262144);
  int*      payA   = (int*)(rx + 2 * 262144);
  int*      payB   = (int*)(rx + 3 * 262144);
  int*      rcounts= (int*)(rx + 4 * 262144);
  int*      rbase  = (int*)(rx + 5 * 262144);

  // Host-side fold_in(key(42), i) = threefry2x32(k=(0,42), x=(0,i)).
  uint32_t fk0[3], fk1[3];
  for (int i = 0; i < 3; i++) {
    uint32_t a = 0u, b = (uint32_t)i;
    threefry2x32(0u, 42u, a, b);
    fk0[i] = a; fk1[i] = b;
  }

  const int B256 = 256;
  // ---------------- CSR build (once) ----------------
  hipMemsetAsync(rank_, 0, (size_t)N * 4, stream);
  indeg_k<<<(E + 255) / 256, B256, 0, stream>>>(dst, rank_, E);
  scan_k<<<1, B256, 0, stream>>>(rank_, rowptr, N);
  cpyint_k<<<(N + 255) / 256, B256, 0, stream>>>(rowptr, curs, N);
  place_k<<<(E + 255) / 256, B256, 0, stream>>>(dst, curs, csr, E);
  sortrow_k<<<(N + 255) / 256, B256, 0, stream>>>(rowptr, csr, N);

  // ---------------- 3 GAT layers ----------------
  for (int i = 0; i < 3; i++) {
    const float* in = (i == 0) ? x : bufB;
    int K = (i == 0) ? ID : HD;
    gemm200_k<<<(N + 127) / 128, B256, 0, stream>>>(in, W[i], bufA, N, K);
    dual_dot_k<<<(N + 3) / 4, B256, 0, stream>>>(bufA, asv[i], adv[i], as_, ad_, N);
    eeden_k<<<(N + 255) / 256, B256, 0, stream>>>(rowptr, csr, src, as_, ad_,
                                                  pk, eeS, den, N);
    gat_out_k<<<(N + 3) / 4, B256, 0, stream>>>(rowptr, pk, eeS, den, bufA,
                                                bv[i], bufB, fk0[i], fk1[i], N);
  }

  // ---------------- SAGPooling loop ----------------
  einit_k<<<(E + 255) / 256, B256, 0, stream>>>(src, dst, csrc, cdst, origA, E, N);
  float* hcur = bufB;
  float* hnext = bufA;
  int* ocur = origA;
  int* onext = origB;
  int n = N;
  while (true) {
    int k = (n + 1) / 2;  // ceil(0.5 n)
    int NB = (n + 255) / 256;
    pool_agg_k<<<(n + 3) / 4, B256, 0, stream>>>(rowptr, csr, csrc, ocur, hcur,
                                                 Wrel, Wroot, bpool, score, n);
    // exact rank via stable 4x8-bit LSD radix sort (tie-proof, O(n));
    // scatter passes emit the next pass's histogram; rscan zeroes counts.
    rhenc_k<<<NB, B256, 0, stream>>>(score, keyA, payA, rcounts, n, NB);
    rscan_k<<<1, B256, 0, stream>>>(rcounts, rbase, NB);
    rscatter_k<<<NB, B256, 0, stream>>>(keyA, payA, rbase, keyB, payB, rcounts, n, NB, 0);
    rscan_k<<<1, B256, 0, stream>>>(rcounts, rbase, NB);
    rscatter_k<<<NB, B256, 0, stream>>>(keyB, payB, rbase, keyA, payA, rcounts, n, NB, 8);
    rscan_k<<<1, B256, 0, stream>>>(rcounts, rbase, NB);
    rscatter_k<<<NB, B256, 0, stream>>>(keyA, payA, rbase, keyB, payB, rcounts, n, NB, 16);
    rscan_k<<<1, B256, 0, stream>>>(rcounts, rbase, NB);
    rscatterF_k<<<NB, B256, 0, stream>>>(keyB, payB, rbase, ocur, onext, perm_, inv_,
                                         n, NB, k);
    gather_k<<<k, B256, 0, stream>>>(hcur, perm_, score, hnext, k);
    remap_k<<<(E + 255) / 256, B256, 0, stream>>>(csrc, cdst, inv_, E);
    { float* t = hcur; hcur = hnext; hnext = t; }
    { int* t = ocur; ocur = onext; onext = t; }
    n = k;
    if (n <= 512) break;
  }

  // ---------------- output: zeros(512,200) with first n rows = h -------------
  hipMemsetAsync(d_out, 0, (size_t)out_size * 4, stream);
  out_copy_k<<<(n * HD + 255) / 256, B256, 0, stream>>>(hcur, (float*)d_out, n * HD);
}